// Round 3
// baseline (1376.249 us; speedup 1.0000x reference)
//
#include <hip/hip_runtime.h>
#include <math.h>

#define BB 16
#define LL 1024
#define EE 256
#define OO 256

// ---------------------------------------------------------------------------
// Kernel 1: fused QKV projection.  C[m][n] = sum_e A[m][e] * W[e][n]
// grid = (M/64, O/64, 3), block = 256 (16x16 threads, 4x4 per thread)
// which==0 -> q (into d_out!), which==1 -> k (ws), which==2 -> v (ws+16MB)
// ---------------------------------------------------------------------------
__global__ __launch_bounds__(256) void qkv_kernel(
    const float* __restrict__ joint, const float* __restrict__ Wq,
    const float* __restrict__ Wk, const float* __restrict__ Wv,
    float* __restrict__ qout, float* __restrict__ kout, float* __restrict__ vout)
{
    const int m0 = blockIdx.x * 64;
    const int n0 = blockIdx.y * 64;
    const int which = blockIdx.z;
    const float* __restrict__ W = (which == 0) ? Wq : ((which == 1) ? Wk : Wv);
    float* __restrict__ outp = (which == 0) ? qout : ((which == 1) ? kout : vout);

    __shared__ float As[64][36];   // row stride 36 floats (16B-aligned, odd bank phase)
    __shared__ float Ws[32][68];   // row stride 68 floats

    const int tid = threadIdx.x;
    const int tx = tid & 15;
    const int ty = tid >> 4;

    float acc[4][4];
    #pragma unroll
    for (int i = 0; i < 4; ++i)
        #pragma unroll
        for (int j = 0; j < 4; ++j) acc[i][j] = 0.f;

    for (int e0 = 0; e0 < EE; e0 += 32) {
        {
            const int r = tid >> 3;
            const int c = (tid & 7) << 2;
            *(float4*)&As[r][c]      = *(const float4*)&joint[(size_t)(m0 + r) * EE + e0 + c];
            *(float4*)&As[r + 32][c] = *(const float4*)&joint[(size_t)(m0 + r + 32) * EE + e0 + c];
            const int wr = tid >> 4;
            const int wc = (tid & 15) << 2;
            *(float4*)&Ws[wr][wc]      = *(const float4*)&W[(size_t)(e0 + wr) * OO + n0 + wc];
            *(float4*)&Ws[wr + 16][wc] = *(const float4*)&W[(size_t)(e0 + wr + 16) * OO + n0 + wc];
        }
        __syncthreads();
        #pragma unroll
        for (int e = 0; e < 32; e += 4) {
            float4 a4[4], w4[4];
            #pragma unroll
            for (int i = 0; i < 4; ++i) a4[i] = *(const float4*)&As[ty * 4 + i][e];
            #pragma unroll
            for (int k = 0; k < 4; ++k) w4[k] = *(const float4*)&Ws[e + k][tx * 4];
            #pragma unroll
            for (int i = 0; i < 4; ++i) {
                acc[i][0] += a4[i].x*w4[0].x + a4[i].y*w4[1].x + a4[i].z*w4[2].x + a4[i].w*w4[3].x;
                acc[i][1] += a4[i].x*w4[0].y + a4[i].y*w4[1].y + a4[i].z*w4[2].y + a4[i].w*w4[3].y;
                acc[i][2] += a4[i].x*w4[0].z + a4[i].y*w4[1].z + a4[i].z*w4[2].z + a4[i].w*w4[3].z;
                acc[i][3] += a4[i].x*w4[0].w + a4[i].y*w4[1].w + a4[i].z*w4[2].w + a4[i].w*w4[3].w;
            }
        }
        __syncthreads();
    }
    #pragma unroll
    for (int i = 0; i < 4; ++i) {
        float4 r4 = make_float4(acc[i][0], acc[i][1], acc[i][2], acc[i][3]);
        *(float4*)&outp[(size_t)(m0 + ty * 4 + i) * OO + n0 + tx * 4] = r4;
    }
}

// ---------------------------------------------------------------------------
// Kernel 2: fused flash-style attention with delta bias + post-softmax mask.
// grid = (L/64, B), block = 256 (16x16 threads).  Per block: 64 q-rows.
// Online softmax over ALL columns (reference masks AFTER softmax); p zeroed
// for j >= T before PV; rows i >= T zeroed at the store.
// NOTE: qm aliases outp (q lives in d_out). Safe: each block reads only its
// own 64 q-rows (all reads precede the epilogue in program order) and writes
// exactly those rows; blocks touch disjoint row sets.
// ---------------------------------------------------------------------------
struct QKTiles { float Qs[64][36]; float Ks[64][36]; };
union SMem { QKTiles qk; float Vs[64][68]; };
static_assert(sizeof(SMem) <= 19 * 1024, "SMem too big");

__global__ __launch_bounds__(256) void attn_kernel(
    const float* __restrict__ qm, const float* __restrict__ km,
    const float* __restrict__ vm, const float* __restrict__ delta,
    const int* __restrict__ traj_len, float* __restrict__ outp)
{
    const int b  = blockIdx.y;
    const int i0 = blockIdx.x * 64;
    const int T  = traj_len[b];
    const int tid = threadIdx.x;
    const int tx = tid & 15;
    const int ty = tid >> 4;

    __shared__ SMem sm;
    __shared__ float Ps[64][68];

    float o[4][4][4];   // [col-chunk][row][col]
    #pragma unroll
    for (int cc = 0; cc < 4; ++cc)
        #pragma unroll
        for (int i = 0; i < 4; ++i)
            #pragma unroll
            for (int j = 0; j < 4; ++j) o[cc][i][j] = 0.f;

    float mrow[4], lrow[4];
    #pragma unroll
    for (int i = 0; i < 4; ++i) { mrow[i] = -INFINITY; lrow[i] = 0.f; }

    const float* __restrict__ qb = qm + (size_t)b * LL * OO;
    const float* __restrict__ kb = km + (size_t)b * LL * OO;
    const float* __restrict__ vb = vm + (size_t)b * LL * OO;

    for (int j0 = 0; j0 < LL; j0 += 64) {
        // ---- init s with delta bias: s[i][j] = delta[b][r][c][0] + delta[b][r][c][1]
        float s[4][4];
        #pragma unroll
        for (int i = 0; i < 4; ++i) {
            const size_t base =
                ((size_t)(b * LL + i0 + ty * 4 + i) * LL + (size_t)(j0 + tx * 4)) * 2;
            float4 d0 = *(const float4*)&delta[base];
            float4 d1 = *(const float4*)&delta[base + 4];
            s[i][0] = d0.x + d0.y;
            s[i][1] = d0.z + d0.w;
            s[i][2] = d1.x + d1.y;
            s[i][3] = d1.z + d1.w;
        }

        // ---- QK^T accumulation, e-chunked
        for (int e0 = 0; e0 < OO; e0 += 32) {
            {
                const int r = tid >> 3;
                const int c = (tid & 7) << 2;
                *(float4*)&sm.qk.Qs[r][c]      = *(const float4*)&qb[(size_t)(i0 + r) * OO + e0 + c];
                *(float4*)&sm.qk.Qs[r + 32][c] = *(const float4*)&qb[(size_t)(i0 + r + 32) * OO + e0 + c];
                *(float4*)&sm.qk.Ks[r][c]      = *(const float4*)&kb[(size_t)(j0 + r) * OO + e0 + c];
                *(float4*)&sm.qk.Ks[r + 32][c] = *(const float4*)&kb[(size_t)(j0 + r + 32) * OO + e0 + c];
            }
            __syncthreads();
            #pragma unroll
            for (int e = 0; e < 32; e += 4) {
                float4 q4[4], k4[4];
                #pragma unroll
                for (int i = 0; i < 4; ++i) q4[i] = *(const float4*)&sm.qk.Qs[ty * 4 + i][e];
                #pragma unroll
                for (int j = 0; j < 4; ++j) k4[j] = *(const float4*)&sm.qk.Ks[tx * 4 + j][e];
                #pragma unroll
                for (int i = 0; i < 4; ++i) {
                    #pragma unroll
                    for (int j = 0; j < 4; ++j) {
                        s[i][j] += q4[i].x*k4[j].x + q4[i].y*k4[j].y
                                 + q4[i].z*k4[j].z + q4[i].w*k4[j].w;
                    }
                }
            }
            __syncthreads();
        }

        // ---- online softmax update (denominator over ALL columns)
        #pragma unroll
        for (int i = 0; i < 4; ++i) {
            float mx = fmaxf(fmaxf(s[i][0], s[i][1]), fmaxf(s[i][2], s[i][3]));
            #pragma unroll
            for (int d = 1; d < 16; d <<= 1) mx = fmaxf(mx, __shfl_xor(mx, d));
            const float mnew = fmaxf(mrow[i], mx);
            const float sc = __expf(mrow[i] - mnew);
            float p0 = __expf(s[i][0] - mnew);
            float p1 = __expf(s[i][1] - mnew);
            float p2 = __expf(s[i][2] - mnew);
            float p3 = __expf(s[i][3] - mnew);
            float rs = p0 + p1 + p2 + p3;
            #pragma unroll
            for (int d = 1; d < 16; d <<= 1) rs += __shfl_xor(rs, d);
            lrow[i] = lrow[i] * sc + rs;
            mrow[i] = mnew;
            // post-softmax column mask (before PV)
            const int jc = j0 + tx * 4;
            if (jc + 0 >= T) p0 = 0.f;
            if (jc + 1 >= T) p1 = 0.f;
            if (jc + 2 >= T) p2 = 0.f;
            if (jc + 3 >= T) p3 = 0.f;
            *(float4*)&Ps[ty * 4 + i][tx * 4] = make_float4(p0, p1, p2, p3);
            #pragma unroll
            for (int cc = 0; cc < 4; ++cc)
                #pragma unroll
                for (int j = 0; j < 4; ++j) o[cc][i][j] *= sc;
        }
        __syncthreads();

        // ---- PV: 4 column-chunks of 64
        #pragma unroll
        for (int cc = 0; cc < 4; ++cc) {
            {
                const int r  = tid >> 2;
                const int c0 = (tid & 3) * 16;
                #pragma unroll
                for (int k = 0; k < 4; ++k) {
                    *(float4*)&sm.Vs[r][c0 + k * 4] =
                        *(const float4*)&vb[(size_t)(j0 + r) * OO + cc * 64 + c0 + k * 4];
                }
            }
            __syncthreads();
            #pragma unroll
            for (int jj = 0; jj < 64; jj += 4) {
                float4 p4[4], v4[4];
                #pragma unroll
                for (int i = 0; i < 4; ++i) p4[i] = *(const float4*)&Ps[ty * 4 + i][jj];
                #pragma unroll
                for (int k = 0; k < 4; ++k) v4[k] = *(const float4*)&sm.Vs[jj + k][tx * 4];
                #pragma unroll
                for (int i = 0; i < 4; ++i) {
                    o[cc][i][0] += p4[i].x*v4[0].x + p4[i].y*v4[1].x + p4[i].z*v4[2].x + p4[i].w*v4[3].x;
                    o[cc][i][1] += p4[i].x*v4[0].y + p4[i].y*v4[1].y + p4[i].z*v4[2].y + p4[i].w*v4[3].y;
                    o[cc][i][2] += p4[i].x*v4[0].z + p4[i].y*v4[1].z + p4[i].z*v4[2].z + p4[i].w*v4[3].z;
                    o[cc][i][3] += p4[i].x*v4[0].w + p4[i].y*v4[1].w + p4[i].z*v4[2].w + p4[i].w*v4[3].w;
                }
            }
            __syncthreads();
        }
    }

    // ---- epilogue: normalize, zero invalid rows, store (overwrites q rows
    // owned by this block only)
    #pragma unroll
    for (int i = 0; i < 4; ++i) {
        const int r = i0 + ty * 4 + i;
        const float inv = 1.f / lrow[i];
        const bool rv = (r < T);
        #pragma unroll
        for (int cc = 0; cc < 4; ++cc) {
            float4 res;
            res.x = rv ? o[cc][i][0] * inv : 0.f;
            res.y = rv ? o[cc][i][1] * inv : 0.f;
            res.z = rv ? o[cc][i][2] * inv : 0.f;
            res.w = rv ? o[cc][i][3] * inv : 0.f;
            *(float4*)&outp[(size_t)(b * LL + r) * OO + cc * 64 + tx * 4] = res;
        }
    }
}

// ---------------------------------------------------------------------------
extern "C" void kernel_launch(void* const* d_in, const int* in_sizes, int n_in,
                              void* d_out, int out_size, void* d_ws, size_t ws_size,
                              hipStream_t stream)
{
    const float* joint    = (const float*)d_in[0];
    const float* delta    = (const float*)d_in[1];
    const int*   traj_len = (const int*)d_in[2];
    const float* Wq       = (const float*)d_in[3];
    const float* Wk       = (const float*)d_in[4];
    const float* Wv       = (const float*)d_in[5];
    float* outp = (float*)d_out;

    const size_t stride = (size_t)BB * LL * OO;   // 4 M elements = 16 MB
    float* q = outp;                 // q lives in d_out (16 MB)
    float* k = (float*)d_ws;         // k: ws[0 .. 16MB)
    float* v = k + stride;           // v: ws[16MB .. 32MB)

    dim3 g1(BB * LL / 64, OO / 64, 3);
    qkv_kernel<<<g1, 256, 0, stream>>>(joint, Wq, Wk, Wv, q, k, v);

    dim3 g2(LL / 64, BB);
    attn_kernel<<<g2, 256, 0, stream>>>(q, k, v, delta, traj_len, outp);
}